// Round 10
// baseline (1946.246 us; speedup 1.0000x reference)
//
#include <hip/hip_runtime.h>

// ---------------------------------------------------------------------------
// Transformer (GateLoop-style) forward, MI355X/gfx950.  Round 10.
//  = round 9 with GEMM wave-tile widened to 128x64 (acc[8][4]) for the big
//    GEMMs: 256x256 block / 8 waves / 512 thr (NOT 16 waves — round-9 lesson:
//    more waves per barrier regressed; more MFMA per wave per barrier wins).
//    - logits / fused(N=6144) / W1: <BM=256,BN=256,WTM=128>
//    - W2: split-K=2 <256,128,64> (proven)   - Wo: <128,128,64> (proven)
//  Same 2-barrier K-loop, same XOR swizzle (conflicts==0), same numerics
//  (per-output accumulation order unchanged -> bitwise identical).
// ---------------------------------------------------------------------------

typedef float fx4 __attribute__((ext_vector_type(4)));
typedef _Float16 f16x8 __attribute__((ext_vector_type(8)));
typedef _Float16 f16x4 __attribute__((ext_vector_type(4)));

#define AS1 __attribute__((address_space(1)))
#define AS3 __attribute__((address_space(3)))

// ---------------------------------------------------------------- transpose
__global__ __launch_bounds__(256) void transpose_f16_kernel(
    const float* __restrict__ in, _Float16* __restrict__ out,
    int K, int N, size_t ostride)
{
    __shared__ float tile[32][33];
    const int b = blockIdx.z;
    in  += (size_t)b * K * N;
    out += (size_t)b * ostride;
    const int k0 = blockIdx.x * 32, n0 = blockIdx.y * 32;
    const int tr = threadIdx.x >> 3;
    const int tc = (threadIdx.x & 7) * 4;
    fx4 v = *(const fx4*)&in[(size_t)(k0 + tr) * N + n0 + tc];
    tile[tr][tc + 0] = v[0]; tile[tr][tc + 1] = v[1];
    tile[tr][tc + 2] = v[2]; tile[tr][tc + 3] = v[3];
    __syncthreads();
    f16x4 o;
    #pragma unroll
    for (int e = 0; e < 4; ++e) o[e] = (_Float16)tile[tc + e][tr];
    *(f16x4*)&out[(size_t)(n0 + tr) * K + k0 + tc] = o;
}

// ---------------------------------------------------------------- embedding
__global__ __launch_bounds__(256) void embed_kernel(
    const int* __restrict__ tokens, const float* __restrict__ emb,
    float* __restrict__ x)
{
    const int row = blockIdx.x;
    const int t = tokens[row];
    const int c = threadIdx.x * 4;
    *(fx4*)&x[(size_t)row * 1024 + c] = *(const fx4*)&emb[(size_t)t * 1024 + c];
}

// ---------------------------------------------------------------- rms -> fp16
__global__ __launch_bounds__(256) void rms_f16_kernel(
    const float* __restrict__ x, const float* __restrict__ g,
    _Float16* __restrict__ outh)
{
    const int row = blockIdx.x;
    const int c = threadIdx.x * 4;
    fx4 v = *(const fx4*)&x[(size_t)row * 1024 + c];
    float ss = v[0]*v[0] + v[1]*v[1] + v[2]*v[2] + v[3]*v[3];
    #pragma unroll
    for (int off = 32; off > 0; off >>= 1) ss += __shfl_down(ss, off, 64);
    __shared__ float wsum[4];
    if ((threadIdx.x & 63) == 0) wsum[threadIdx.x >> 6] = ss;
    __syncthreads();
    const float nrm = sqrtf(wsum[0] + wsum[1] + wsum[2] + wsum[3]);
    const float scale = 32.0f / fmaxf(nrm, 1e-12f);
    fx4 gg = *(const fx4*)&g[c];
    f16x4 o;
    #pragma unroll
    for (int e = 0; e < 4; ++e) o[e] = (_Float16)(v[e] * scale * gg[e]);
    *(f16x4*)&outh[(size_t)row * 1024 + c] = o;
}

// ---------------------------------------------------------------- scan prep
__global__ __launch_bounds__(256) void prep_qkv_kernel(
    const float* __restrict__ qkv, float* __restrict__ qT, float* __restrict__ kvT)
{
    __shared__ float tq[32][33], tkv[32][33];
    const int n0 = blockIdx.x * 32, h0 = blockIdx.y * 32, b = blockIdx.z;
    const int tr = threadIdx.x >> 3;
    const int tc = (threadIdx.x & 7) * 4;
    const float* row = qkv + ((size_t)b * 2048 + n0 + tr) * 3072;
    fx4 qv = *(const fx4*)&row[h0 + tc];
    fx4 kv = *(const fx4*)&row[1024 + h0 + tc];
    fx4 vv = *(const fx4*)&row[2048 + h0 + tc];
    #pragma unroll
    for (int e = 0; e < 4; ++e) { tq[tr][tc + e] = qv[e]; tkv[tr][tc + e] = kv[e] * vv[e]; }
    __syncthreads();
    fx4 oq, okv;
    #pragma unroll
    for (int e = 0; e < 4; ++e) { oq[e] = tq[tc + e][tr]; okv[e] = tkv[tc + e][tr]; }
    const size_t ob = ((size_t)b * 1024 + h0 + tr) * 2048 + n0 + tc;
    *(fx4*)&qT[ob] = oq;
    *(fx4*)&kvT[ob] = okv;
}

__global__ __launch_bounds__(256) void prep_a_kernel(
    const float* __restrict__ al, float* __restrict__ aReT, float* __restrict__ aImT)
{
    __shared__ float tre[32][33], tim[32][33];
    const int n0 = blockIdx.x * 32, h0 = blockIdx.y * 32, b = blockIdx.z;
    const int tr = threadIdx.x >> 3;
    const int tcf = (threadIdx.x & 7) * 8;
    const float* row = al + ((size_t)b * 2048 + n0 + tr) * 2048 + 2 * h0;
    fx4 v0 = *(const fx4*)&row[tcf];
    fx4 v1 = *(const fx4*)&row[tcf + 4];
    #pragma unroll
    for (int p = 0; p < 4; ++p) {
        float re = (p < 2) ? v0[2 * p] : v1[2 * (p - 2)];
        float im = (p < 2) ? v0[2 * p + 1] : v1[2 * (p - 2) + 1];
        float r = sqrtf(re * re + im * im);
        float sg = 1.0f / (1.0f + expf(-r));
        float a_re, a_im;
        if (r > 0.0f) { float inv = sg / r; a_re = re * inv; a_im = im * inv; }
        else          { a_re = sg; a_im = 0.0f; }
        tre[tr][tcf / 2 + p] = a_re;
        tim[tr][tcf / 2 + p] = a_im;
    }
    __syncthreads();
    const int tc = (threadIdx.x & 7) * 4;
    fx4 ore, oim;
    #pragma unroll
    for (int e = 0; e < 4; ++e) { ore[e] = tre[tc + e][tr]; oim[e] = tim[tc + e][tr]; }
    const size_t ob = ((size_t)b * 1024 + h0 + tr) * 2048 + n0 + tc;
    *(fx4*)&aReT[ob] = ore;
    *(fx4*)&aImT[ob] = oim;
}

// ---------------------------------------------------------------- gate-loop scan
__device__ __forceinline__ int pidx(int i) { return i + (i >> 5); }

__global__ __launch_bounds__(256) void scanT_kernel(
    const float* __restrict__ kvT, const float* __restrict__ aReT,
    const float* __restrict__ aImT, const float* __restrict__ qT,
    float* __restrict__ yT)
{
    const int tid = threadIdx.x;
    const size_t base = (size_t)blockIdx.x * 2048;
    __shared__ float s_re[2048 + 64], s_im[2048 + 64], s_kv[2048 + 64];

    for (int i = tid; i < 512; i += 256) {
        fx4 kv = *(const fx4*)&kvT[base + i * 4];
        fx4 re = *(const fx4*)&aReT[base + i * 4];
        fx4 im = *(const fx4*)&aImT[base + i * 4];
        #pragma unroll
        for (int e = 0; e < 4; ++e) {
            const int j = pidx(i * 4 + e);
            s_kv[j] = kv[e]; s_re[j] = re[e]; s_im[j] = im[e];
        }
    }
    __syncthreads();

    for (int d = 0; d < 11; ++d) {
        const int half = 1 << d, stride = half << 1;
        const int npairs = 2048 >> (d + 1);
        for (int i = tid; i < npairs; i += 256) {
            const int rj = pidx(i * stride + stride - 1);
            const int lj = pidx(i * stride + stride - 1 - half);
            float lre = s_re[lj], lim = s_im[lj], lkv = s_kv[lj];
            float rre = s_re[rj], rim = s_im[rj], rkv = s_kv[rj];
            s_kv[rj] = rre * lkv + rkv;
            s_re[rj] = rre * lre - rim * lim;
            s_im[rj] = rre * lim + rim * lre;
        }
        __syncthreads();
    }
    for (int d = 9; d >= 0; --d) {
        const int w = 1 << d;
        const int nupd = (2048 >> (d + 1)) - 1;
        for (int t = tid; t < nupd; t += 256) {
            const int i = t + 1;
            const int rj = pidx((2 * i + 1) * w - 1);
            const int lj = pidx(2 * i * w - 1);
            float lre = s_re[lj], lim = s_im[lj], lkv = s_kv[lj];
            float rre = s_re[rj], rim = s_im[rj], rkv = s_kv[rj];
            s_kv[rj] = rre * lkv + rkv;
            s_re[rj] = rre * lre - rim * lim;
            s_im[rj] = rre * lim + rim * lre;
        }
        __syncthreads();
    }
    for (int i = tid; i < 512; i += 256) {
        fx4 q = *(const fx4*)&qT[base + i * 4];
        fx4 o;
        #pragma unroll
        for (int e = 0; e < 4; ++e) o[e] = q[e] * s_kv[pidx(i * 4 + e)];
        *(fx4*)&yT[base + i * 4] = o;
    }
}

// ---------------------------------------------------------------- gating
__global__ __launch_bounds__(256) void gate_kernel(
    const float* __restrict__ G, const float* __restrict__ yT,
    _Float16* __restrict__ gated)
{
    __shared__ float ty[32][33];
    const int n0 = blockIdx.x * 32, h0 = blockIdx.y * 32, b = blockIdx.z;
    const int tr = threadIdx.x >> 3;
    const int tc = (threadIdx.x & 7) * 4;
    fx4 yv = *(const fx4*)&yT[((size_t)b * 1024 + h0 + tr) * 2048 + n0 + tc];
    #pragma unroll
    for (int e = 0; e < 4; ++e) ty[tr][tc + e] = yv[e];
    __syncthreads();
    const size_t grow = ((size_t)b * 2048 + n0 + tr) * 1024 + h0 + tc;
    fx4 gv = *(const fx4*)&G[grow];
    f16x4 o;
    #pragma unroll
    for (int e = 0; e < 4; ++e) {
        const float s = gv[e] / (1.0f + expf(-gv[e]));   // silu
        o[e] = (_Float16)(s * ty[tc + e][tr]);
    }
    *(f16x4*)&gated[grow] = o;
}

// ---------------------------------------------------------------- W2 combine
__global__ __launch_bounds__(256) void combine2_kernel(
    const float* __restrict__ p, const float* __restrict__ bias,
    float* __restrict__ x)
{
    const size_t i = ((size_t)blockIdx.x * 256 + threadIdx.x) * 4;
    fx4 a = *(const fx4*)&p[i];
    fx4 b = *(const fx4*)&p[i + (size_t)4096 * 1024];
    fx4 xx = *(const fx4*)&x[i];
    fx4 bb = *(const fx4*)&bias[(int)(i & 1023)];
    fx4 o;
    #pragma unroll
    for (int e = 0; e < 4; ++e) o[e] = xx[e] + (a[e] + b[e] + bb[e]);
    *(fx4*)&x[i] = o;
}

// ---------------------------------------------------------------- GEMM (fp16)
// C[M,N] = A[M,K](fp16) * Bt[N,K]^T(fp16), f32 accumulate.
// Block tile BMxBN; wave tile WTM x 64 (acc[WTM/16][4]); waves = (BM/WTM)*(BN/64);
// threads = waves*64.  Single-buffer LDS, 2-barrier K-loop, XOR swizzle
// (16B granules, involution src+read; conflicts == 0 verified r5-r9).
// K = loop extent, Kld = row stride (split-K: K < Kld); blockIdx.z = K-slice.
// EPI: 0=store f32 (+bz*M*N), 2=Cf+=v, 4=Ch=f16(gelu(v+bias)),
//      6=fused routing by global col: <3072 qkv | <5120 al+bias | else G
template<int EPI, int BM, int BN, int WTM>
__global__ __launch_bounds__((BM / WTM) * (BN / 64) * 64) void gemm_kernel(
    const _Float16* __restrict__ A, const _Float16* __restrict__ Bt,
    const float* __restrict__ bias,
    float* __restrict__ Cf, float* __restrict__ Cf2, float* __restrict__ Cf3,
    _Float16* __restrict__ Ch,
    int M, int N, int K, int Kld)
{
    constexpr int NW      = BN / 64;              // waves along N
    constexpr int THREADS = (BM / WTM) * NW * 64;
    constexpr int M_REP   = WTM / 16;             // 16x16 frags along M per wave
    __shared__ __align__(16) _Float16 As[BM * 64];
    __shared__ __align__(16) _Float16 Bs[BN * 64];
    const int tid  = threadIdx.x;
    const int lane = tid & 63;
    const int wave = tid >> 6;
    const int bm = blockIdx.x, bn = blockIdx.y;
    const int bz = blockIdx.z;
    const int wm = (wave / NW) * WTM;
    const int wn = (wave % NW) * 64;

    A  += (size_t)bz * K;
    Bt += (size_t)bz * K;
    if (EPI == 0) Cf += (size_t)bz * M * N;

    fx4 acc[M_REP][4] = {};

    const size_t aRow0 = (size_t)bm * BM;
    const size_t bRow0 = (size_t)bn * BN;

    for (int k0 = 0; k0 < K; k0 += 64) {
        constexpr int QA = BM * 8 / THREADS;
        #pragma unroll
        for (int q = 0; q < QA; ++q) {
            const int chunk = q * THREADS + tid;
            const int row = chunk >> 3;
            const int slot = chunk & 7;
            const int gs = slot ^ (row & 7);
            const size_t aoff = (aRow0 + row) * (size_t)Kld + k0 + gs * 8;
            __builtin_amdgcn_global_load_lds((const AS1 void*)(A + aoff),
                (AS3 void*)((char*)As + chunk * 16), 16, 0, 0);
        }
        constexpr int QB = BN * 8 / THREADS;
        #pragma unroll
        for (int q = 0; q < QB; ++q) {
            const int chunk = q * THREADS + tid;
            const int row = chunk >> 3;
            const int slot = chunk & 7;
            const int gs = slot ^ (row & 7);
            const size_t boff = (bRow0 + row) * (size_t)Kld + k0 + gs * 8;
            __builtin_amdgcn_global_load_lds((const AS1 void*)(Bt + boff),
                (AS3 void*)((char*)Bs + chunk * 16), 16, 0, 0);
        }
        __syncthreads();   // drains vmcnt(0): staged data visible

        #pragma unroll
        for (int kk = 0; kk < 2; ++kk) {
            const int sw = ((kk * 4 + (lane >> 4)) ^ (lane & 7)) * 16;
            f16x8 af[M_REP], bf[4];
            #pragma unroll
            for (int i = 0; i < M_REP; ++i) {
                const int row = wm + i * 16 + (lane & 15);
                af[i] = *(const f16x8*)((const char*)As + row * 128 + sw);
            }
            #pragma unroll
            for (int j = 0; j < 4; ++j) {
                const int row = wn + j * 16 + (lane & 15);
                bf[j] = *(const f16x8*)((const char*)Bs + row * 128 + sw);
            }
            #pragma unroll
            for (int i = 0; i < M_REP; ++i)
                #pragma unroll
                for (int j = 0; j < 4; ++j)
                    acc[i][j] = __builtin_amdgcn_mfma_f32_16x16x32_f16(
                        af[i], bf[j], acc[i][j], 0, 0, 0);
        }
        __syncthreads();   // all reads done before next staging overwrites
    }

    // epilogue: C/D layout col=lane&15, row=(lane>>4)*4+r
    const int col_l = lane & 15, row_l = (lane >> 4) * 4;
    #pragma unroll
    for (int i = 0; i < M_REP; ++i) {
        #pragma unroll
        for (int j = 0; j < 4; ++j) {
            #pragma unroll
            for (int r = 0; r < 4; ++r) {
                const int row = bm * BM + wm + i * 16 + row_l + r;
                const int col = bn * BN + wn + j * 16 + col_l;
                const float v = acc[i][j][r];
                if (EPI == 0) {
                    Cf[(size_t)row * N + col] = v;
                } else if (EPI == 2) {
                    Cf[(size_t)row * N + col] += v;
                } else if (EPI == 4) {
                    const float t = v + bias[col];
                    const float gelu = 0.5f * t * (1.0f + erff(t * 0.70710678118654752f));
                    Ch[(size_t)row * N + col] = (_Float16)gelu;
                } else if (EPI == 6) {
                    if (col < 3072)      Cf [(size_t)row * 3072 + col] = v;
                    else if (col < 5120) Cf2[(size_t)row * 2048 + (col - 3072)] = v + bias[col - 3072];
                    else                 Cf3[(size_t)row * 1024 + (col - 5120)] = v;
                }
            }
        }
    }
}

// ---------------------------------------------------------------- host
extern "C" void kernel_launch(void* const* d_in, const int* in_sizes, int n_in,
                              void* d_out, int out_size, void* d_ws, size_t ws_size,
                              hipStream_t stream)
{
    const int*   tokens = (const int*)d_in[0];
    const float* emb  = (const float*)d_in[1];
    const float* g1   = (const float*)d_in[2];
    const float* Wqkv = (const float*)d_in[3];
    const float* Wa   = (const float*)d_in[4];
    const float* ba   = (const float*)d_in[5];
    const float* Wg   = (const float*)d_in[6];
    const float* Wo   = (const float*)d_in[7];
    const float* g2   = (const float*)d_in[8];
    const float* W1   = (const float*)d_in[9];
    const float* b1   = (const float*)d_in[10];
    const float* W2   = (const float*)d_in[11];
    const float* b2   = (const float*)d_in[12];
    const float* gf   = (const float*)d_in[13];
    const float* Wl   = (const float*)d_in[14];
    float* out = (float*)d_out;

    char* ws = (char*)d_ws;
    size_t off = 0;
    auto take = [&](size_t bytes) {
        char* p = ws + off; off += (bytes + 255) & ~(size_t)255; return p;
    };

    // fp16 weights
    _Float16* wcat = (_Float16*)take((size_t)4 * 6144 * 1024 * 2);   // [Wqkv|Wa|Wg]^T per layer
    _Float16* wo   = (_Float16*)take((size_t)4 * 1024 * 1024 * 2);
    _Float16* w1   = (_Float16*)take((size_t)4 * 4096 * 1024 * 2);
    _Float16* w2   = (_Float16*)take((size_t)4 * 1024 * 4096 * 2);
    // region shared by 4x16MiB scan scratch (layers) and Wl fp16 (62.5MiB, end)
    char*     wlRegion = take((size_t)64 << 20);
    _Float16* wl   = (_Float16*)wlRegion;
    float*    x    = (float*)take((size_t)4096 * 1024 * 4);
    _Float16* xn   = (_Float16*)take((size_t)4096 * 1024 * 2);
    float*    qkvb = (float*)take((size_t)4096 * 3072 * 4);   // 48MiB (also hosts h fp16 33.5MiB)
    float*    alb  = (float*)take((size_t)4096 * 2048 * 4);   // 32MiB (al / yT+gated / W2 partials)
    float*    G    = (float*)take((size_t)4096 * 1024 * 4);   // 16MiB

    float* qT   = (float*)wlRegion;
    float* kvT  = (float*)(wlRegion + ((size_t)16 << 20));
    float* aReT = (float*)(wlRegion + ((size_t)32 << 20));
    float* aImT = (float*)(wlRegion + ((size_t)48 << 20));
    float*    yT    = alb;                                           // [0,16MiB)
    _Float16* gated = (_Float16*)((char*)alb + ((size_t)16 << 20));  // 8.4MiB
    _Float16* h     = (_Float16*)qkvb;                               // 33.5MiB
    float*    part  = alb;   // W2 split-K partials: 2 x 16MiB (al/yT/gated dead)

    const dim3 blk(256);

    // weight transposes (f32 [K][N] -> fp16 [N][K])
    transpose_f16_kernel<<<dim3(32,  96, 4), blk, 0, stream>>>(Wqkv, wcat,               1024, 3072, (size_t)6144 * 1024);
    transpose_f16_kernel<<<dim3(32,  64, 4), blk, 0, stream>>>(Wa,   wcat + 3072 * 1024, 1024, 2048, (size_t)6144 * 1024);
    transpose_f16_kernel<<<dim3(32,  32, 4), blk, 0, stream>>>(Wg,   wcat + 5120 * 1024, 1024, 1024, (size_t)6144 * 1024);
    transpose_f16_kernel<<<dim3(32,  32, 4), blk, 0, stream>>>(Wo,   wo,  1024, 1024, (size_t)1024 * 1024);
    transpose_f16_kernel<<<dim3(32, 128, 4), blk, 0, stream>>>(W1,   w1,  1024, 4096, (size_t)4096 * 1024);
    transpose_f16_kernel<<<dim3(128, 32, 4), blk, 0, stream>>>(W2,   w2,  4096, 1024, (size_t)1024 * 4096);

    embed_kernel<<<4096, blk, 0, stream>>>(tokens, emb, x);

    for (int i = 0; i < 4; ++i) {
        rms_f16_kernel<<<4096, blk, 0, stream>>>(x, g1 + i * 1024, xn);
        gemm_kernel<6, 256, 256, 128><<<dim3(16, 24), dim3(512), 0, stream>>>(
            xn, wcat + (size_t)i * 6144 * 1024, ba + i * 2048,
            qkvb, alb, G, nullptr, 4096, 6144, 1024, 1024);
        prep_qkv_kernel<<<dim3(64, 32, 2), blk, 0, stream>>>(qkvb, qT, kvT);
        prep_a_kernel<<<dim3(64, 32, 2), blk, 0, stream>>>(alb, aReT, aImT);
        scanT_kernel<<<2048, blk, 0, stream>>>(kvT, aReT, aImT, qT, yT);
        gate_kernel<<<dim3(64, 32, 2), blk, 0, stream>>>(G, yT, gated);
        gemm_kernel<2, 128, 128, 64><<<dim3(32, 8), blk, 0, stream>>>(
            gated, wo + (size_t)i * 1024 * 1024, nullptr,
            x, nullptr, nullptr, nullptr, 4096, 1024, 1024, 1024);
        rms_f16_kernel<<<4096, blk, 0, stream>>>(x, g2 + i * 1024, xn);
        gemm_kernel<4, 256, 256, 128><<<dim3(16, 16), dim3(512), 0, stream>>>(
            xn, w1 + (size_t)i * 4096 * 1024, b1 + i * 4096,
            nullptr, nullptr, nullptr, h, 4096, 4096, 1024, 1024);
        // W2 split-K=2: partials then deterministic combine (+bias, += x)
        gemm_kernel<0, 256, 128, 64><<<dim3(16, 8, 2), dim3(512), 0, stream>>>(
            h, w2 + (size_t)i * 1024 * 4096, nullptr,
            part, nullptr, nullptr, nullptr, 4096, 1024, 2048, 4096);
        combine2_kernel<<<4096, blk, 0, stream>>>(part, b2 + i * 1024, x);
    }

    // Wl transpose deferred: its region was scan scratch during the layers
    transpose_f16_kernel<<<dim3(32, 1000, 1), blk, 0, stream>>>(Wl, wl, 1024, 32000, 0);

    rms_f16_kernel<<<4096, blk, 0, stream>>>(x, gf, xn);
    gemm_kernel<0, 256, 256, 128><<<dim3(16, 125), dim3(512), 0, stream>>>(
        xn, wl, nullptr, out, nullptr, nullptr, nullptr, 4096, 32000, 1024, 1024);
}

// Round 11
// 1627.052 us; speedup vs baseline: 1.1962x; 1.1962x over previous
//
#include <hip/hip_runtime.h>

// ---------------------------------------------------------------------------
// Transformer (GateLoop-style) forward, MI355X/gfx950.  Round 11.
//  Known-best combination (r8 geometry + r9 Wo/W2) + epilogue fusions:
//    - logits / fused(N=6144) / W1: <256,128,WTM=64> 8 waves (r8 optimum:
//      312us logits, 43% occ — r9 16-wave and r10 wide-wave both regressed)
//    - Wo: <128,128,64> grid 256   - W2: split-K=2 <256,128,64> + combine
//    - combine2+RMS fused (block == one row), embed+RMS fused (layer 0)
//  2-barrier K-loop, XOR swizzle (conflicts==0), bitwise-identical GEMMs.
// ---------------------------------------------------------------------------

typedef float fx4 __attribute__((ext_vector_type(4)));
typedef _Float16 f16x8 __attribute__((ext_vector_type(8)));
typedef _Float16 f16x4 __attribute__((ext_vector_type(4)));

#define AS1 __attribute__((address_space(1)))
#define AS3 __attribute__((address_space(3)))

// ---------------------------------------------------------------- transpose
__global__ __launch_bounds__(256) void transpose_f16_kernel(
    const float* __restrict__ in, _Float16* __restrict__ out,
    int K, int N, size_t ostride)
{
    __shared__ float tile[32][33];
    const int b = blockIdx.z;
    in  += (size_t)b * K * N;
    out += (size_t)b * ostride;
    const int k0 = blockIdx.x * 32, n0 = blockIdx.y * 32;
    const int tr = threadIdx.x >> 3;
    const int tc = (threadIdx.x & 7) * 4;
    fx4 v = *(const fx4*)&in[(size_t)(k0 + tr) * N + n0 + tc];
    tile[tr][tc + 0] = v[0]; tile[tr][tc + 1] = v[1];
    tile[tr][tc + 2] = v[2]; tile[tr][tc + 3] = v[3];
    __syncthreads();
    f16x4 o;
    #pragma unroll
    for (int e = 0; e < 4; ++e) o[e] = (_Float16)tile[tc + e][tr];
    *(f16x4*)&out[(size_t)(n0 + tr) * K + k0 + tc] = o;
}

// ---------------------------------------------------------------- row RMS helper
__device__ __forceinline__ float row_rms_scale(float ss) {
    #pragma unroll
    for (int off = 32; off > 0; off >>= 1) ss += __shfl_down(ss, off, 64);
    __shared__ float wsum[4];
    if ((threadIdx.x & 63) == 0) wsum[threadIdx.x >> 6] = ss;
    __syncthreads();
    const float nrm = sqrtf(wsum[0] + wsum[1] + wsum[2] + wsum[3]);
    return 32.0f / fmaxf(nrm, 1e-12f);
}

// ---------------------------------------------------------------- embed + rms
__global__ __launch_bounds__(256) void embed_rms_kernel(
    const int* __restrict__ tokens, const float* __restrict__ emb,
    const float* __restrict__ g, float* __restrict__ x, _Float16* __restrict__ xn)
{
    const int row = blockIdx.x;
    const int t = tokens[row];
    const int c = threadIdx.x * 4;
    fx4 v = *(const fx4*)&emb[(size_t)t * 1024 + c];
    *(fx4*)&x[(size_t)row * 1024 + c] = v;
    const float scale = row_rms_scale(v[0]*v[0] + v[1]*v[1] + v[2]*v[2] + v[3]*v[3]);
    fx4 gg = *(const fx4*)&g[c];
    f16x4 o;
    #pragma unroll
    for (int e = 0; e < 4; ++e) o[e] = (_Float16)(v[e] * scale * gg[e]);
    *(f16x4*)&xn[(size_t)row * 1024 + c] = o;
}

// ---------------------------------------------------------------- rms -> fp16
__global__ __launch_bounds__(256) void rms_f16_kernel(
    const float* __restrict__ x, const float* __restrict__ g,
    _Float16* __restrict__ outh)
{
    const int row = blockIdx.x;
    const int c = threadIdx.x * 4;
    fx4 v = *(const fx4*)&x[(size_t)row * 1024 + c];
    const float scale = row_rms_scale(v[0]*v[0] + v[1]*v[1] + v[2]*v[2] + v[3]*v[3]);
    fx4 gg = *(const fx4*)&g[c];
    f16x4 o;
    #pragma unroll
    for (int e = 0; e < 4; ++e) o[e] = (_Float16)(v[e] * scale * gg[e]);
    *(f16x4*)&outh[(size_t)row * 1024 + c] = o;
}

// ---------------------------------------------------------------- scan prep
__global__ __launch_bounds__(256) void prep_qkv_kernel(
    const float* __restrict__ qkv, float* __restrict__ qT, float* __restrict__ kvT)
{
    __shared__ float tq[32][33], tkv[32][33];
    const int n0 = blockIdx.x * 32, h0 = blockIdx.y * 32, b = blockIdx.z;
    const int tr = threadIdx.x >> 3;
    const int tc = (threadIdx.x & 7) * 4;
    const float* row = qkv + ((size_t)b * 2048 + n0 + tr) * 3072;
    fx4 qv = *(const fx4*)&row[h0 + tc];
    fx4 kv = *(const fx4*)&row[1024 + h0 + tc];
    fx4 vv = *(const fx4*)&row[2048 + h0 + tc];
    #pragma unroll
    for (int e = 0; e < 4; ++e) { tq[tr][tc + e] = qv[e]; tkv[tr][tc + e] = kv[e] * vv[e]; }
    __syncthreads();
    fx4 oq, okv;
    #pragma unroll
    for (int e = 0; e < 4; ++e) { oq[e] = tq[tc + e][tr]; okv[e] = tkv[tc + e][tr]; }
    const size_t ob = ((size_t)b * 1024 + h0 + tr) * 2048 + n0 + tc;
    *(fx4*)&qT[ob] = oq;
    *(fx4*)&kvT[ob] = okv;
}

__global__ __launch_bounds__(256) void prep_a_kernel(
    const float* __restrict__ al, float* __restrict__ aReT, float* __restrict__ aImT)
{
    __shared__ float tre[32][33], tim[32][33];
    const int n0 = blockIdx.x * 32, h0 = blockIdx.y * 32, b = blockIdx.z;
    const int tr = threadIdx.x >> 3;
    const int tcf = (threadIdx.x & 7) * 8;
    const float* row = al + ((size_t)b * 2048 + n0 + tr) * 2048 + 2 * h0;
    fx4 v0 = *(const fx4*)&row[tcf];
    fx4 v1 = *(const fx4*)&row[tcf + 4];
    #pragma unroll
    for (int p = 0; p < 4; ++p) {
        float re = (p < 2) ? v0[2 * p] : v1[2 * (p - 2)];
        float im = (p < 2) ? v0[2 * p + 1] : v1[2 * (p - 2) + 1];
        float r = sqrtf(re * re + im * im);
        float sg = 1.0f / (1.0f + expf(-r));
        float a_re, a_im;
        if (r > 0.0f) { float inv = sg / r; a_re = re * inv; a_im = im * inv; }
        else          { a_re = sg; a_im = 0.0f; }
        tre[tr][tcf / 2 + p] = a_re;
        tim[tr][tcf / 2 + p] = a_im;
    }
    __syncthreads();
    const int tc = (threadIdx.x & 7) * 4;
    fx4 ore, oim;
    #pragma unroll
    for (int e = 0; e < 4; ++e) { ore[e] = tre[tc + e][tr]; oim[e] = tim[tc + e][tr]; }
    const size_t ob = ((size_t)b * 1024 + h0 + tr) * 2048 + n0 + tc;
    *(fx4*)&aReT[ob] = ore;
    *(fx4*)&aImT[ob] = oim;
}

// ---------------------------------------------------------------- gate-loop scan
__device__ __forceinline__ int pidx(int i) { return i + (i >> 5); }

__global__ __launch_bounds__(256) void scanT_kernel(
    const float* __restrict__ kvT, const float* __restrict__ aReT,
    const float* __restrict__ aImT, const float* __restrict__ qT,
    float* __restrict__ yT)
{
    const int tid = threadIdx.x;
    const size_t base = (size_t)blockIdx.x * 2048;
    __shared__ float s_re[2048 + 64], s_im[2048 + 64], s_kv[2048 + 64];

    for (int i = tid; i < 512; i += 256) {
        fx4 kv = *(const fx4*)&kvT[base + i * 4];
        fx4 re = *(const fx4*)&aReT[base + i * 4];
        fx4 im = *(const fx4*)&aImT[base + i * 4];
        #pragma unroll
        for (int e = 0; e < 4; ++e) {
            const int j = pidx(i * 4 + e);
            s_kv[j] = kv[e]; s_re[j] = re[e]; s_im[j] = im[e];
        }
    }
    __syncthreads();

    for (int d = 0; d < 11; ++d) {
        const int half = 1 << d, stride = half << 1;
        const int npairs = 2048 >> (d + 1);
        for (int i = tid; i < npairs; i += 256) {
            const int rj = pidx(i * stride + stride - 1);
            const int lj = pidx(i * stride + stride - 1 - half);
            float lre = s_re[lj], lim = s_im[lj], lkv = s_kv[lj];
            float rre = s_re[rj], rim = s_im[rj], rkv = s_kv[rj];
            s_kv[rj] = rre * lkv + rkv;
            s_re[rj] = rre * lre - rim * lim;
            s_im[rj] = rre * lim + rim * lre;
        }
        __syncthreads();
    }
    for (int d = 9; d >= 0; --d) {
        const int w = 1 << d;
        const int nupd = (2048 >> (d + 1)) - 1;
        for (int t = tid; t < nupd; t += 256) {
            const int i = t + 1;
            const int rj = pidx((2 * i + 1) * w - 1);
            const int lj = pidx(2 * i * w - 1);
            float lre = s_re[lj], lim = s_im[lj], lkv = s_kv[lj];
            float rre = s_re[rj], rim = s_im[rj], rkv = s_kv[rj];
            s_kv[rj] = rre * lkv + rkv;
            s_re[rj] = rre * lre - rim * lim;
            s_im[rj] = rre * lim + rim * lre;
        }
        __syncthreads();
    }
    for (int i = tid; i < 512; i += 256) {
        fx4 q = *(const fx4*)&qT[base + i * 4];
        fx4 o;
        #pragma unroll
        for (int e = 0; e < 4; ++e) o[e] = q[e] * s_kv[pidx(i * 4 + e)];
        *(fx4*)&yT[base + i * 4] = o;
    }
}

// ---------------------------------------------------------------- gating
__global__ __launch_bounds__(256) void gate_kernel(
    const float* __restrict__ G, const float* __restrict__ yT,
    _Float16* __restrict__ gated)
{
    __shared__ float ty[32][33];
    const int n0 = blockIdx.x * 32, h0 = blockIdx.y * 32, b = blockIdx.z;
    const int tr = threadIdx.x >> 3;
    const int tc = (threadIdx.x & 7) * 4;
    fx4 yv = *(const fx4*)&yT[((size_t)b * 1024 + h0 + tr) * 2048 + n0 + tc];
    #pragma unroll
    for (int e = 0; e < 4; ++e) ty[tr][tc + e] = yv[e];
    __syncthreads();
    const size_t grow = ((size_t)b * 2048 + n0 + tr) * 1024 + h0 + tc;
    fx4 gv = *(const fx4*)&G[grow];
    f16x4 o;
    #pragma unroll
    for (int e = 0; e < 4; ++e) {
        const float s = gv[e] / (1.0f + expf(-gv[e]));   // silu
        o[e] = (_Float16)(s * ty[tc + e][tr]);
    }
    *(f16x4*)&gated[grow] = o;
}

// ---------------------------------------------------------------- W2 combine + next-layer RMS
// Block == one row: x += p0 + p1 + bias; xn = fp16(rms(x) * g)
__global__ __launch_bounds__(256) void combine2_rms_kernel(
    const float* __restrict__ p, const float* __restrict__ bias,
    const float* __restrict__ g, float* __restrict__ x, _Float16* __restrict__ xn)
{
    const int row = blockIdx.x;
    const int c = threadIdx.x * 4;
    const size_t i = (size_t)row * 1024 + c;
    fx4 a = *(const fx4*)&p[i];
    fx4 b = *(const fx4*)&p[i + (size_t)4096 * 1024];
    fx4 xx = *(const fx4*)&x[i];
    fx4 bb = *(const fx4*)&bias[c];
    fx4 o;
    #pragma unroll
    for (int e = 0; e < 4; ++e) o[e] = xx[e] + (a[e] + b[e] + bb[e]);
    *(fx4*)&x[i] = o;
    const float scale = row_rms_scale(o[0]*o[0] + o[1]*o[1] + o[2]*o[2] + o[3]*o[3]);
    fx4 gg = *(const fx4*)&g[c];
    f16x4 oh;
    #pragma unroll
    for (int e = 0; e < 4; ++e) oh[e] = (_Float16)(o[e] * scale * gg[e]);
    *(f16x4*)&xn[i] = oh;
}

// ---------------------------------------------------------------- GEMM (fp16)
// C[M,N] = A[M,K](fp16) * Bt[N,K]^T(fp16), f32 accumulate.
// Block tile BMxBN; wave tile WTM x 64; waves = (BM/WTM)*(BN/64).
// Single-buffer LDS, 2-barrier K-loop, XOR swizzle (conflicts==0, r5-r10).
// K = loop extent, Kld = row stride (split-K: K < Kld); blockIdx.z = K-slice.
// EPI: 0=store f32 (+bz*M*N), 2=Cf+=v, 4=Ch=f16(gelu(v+bias)),
//      6=fused routing by global col: <3072 qkv | <5120 al+bias | else G
template<int EPI, int BM, int BN, int WTM>
__global__ __launch_bounds__((BM / WTM) * (BN / 64) * 64) void gemm_kernel(
    const _Float16* __restrict__ A, const _Float16* __restrict__ Bt,
    const float* __restrict__ bias,
    float* __restrict__ Cf, float* __restrict__ Cf2, float* __restrict__ Cf3,
    _Float16* __restrict__ Ch,
    int M, int N, int K, int Kld)
{
    constexpr int NW      = BN / 64;
    constexpr int THREADS = (BM / WTM) * NW * 64;
    constexpr int M_REP   = WTM / 16;
    __shared__ __align__(16) _Float16 As[BM * 64];
    __shared__ __align__(16) _Float16 Bs[BN * 64];
    const int tid  = threadIdx.x;
    const int lane = tid & 63;
    const int wave = tid >> 6;
    const int bm = blockIdx.x, bn = blockIdx.y;
    const int bz = blockIdx.z;
    const int wm = (wave / NW) * WTM;
    const int wn = (wave % NW) * 64;

    A  += (size_t)bz * K;
    Bt += (size_t)bz * K;
    if (EPI == 0) Cf += (size_t)bz * M * N;

    fx4 acc[M_REP][4] = {};

    const size_t aRow0 = (size_t)bm * BM;
    const size_t bRow0 = (size_t)bn * BN;

    for (int k0 = 0; k0 < K; k0 += 64) {
        constexpr int QA = BM * 8 / THREADS;
        #pragma unroll
        for (int q = 0; q < QA; ++q) {
            const int chunk = q * THREADS + tid;
            const int row = chunk >> 3;
            const int slot = chunk & 7;
            const int gs = slot ^ (row & 7);
            const size_t aoff = (aRow0 + row) * (size_t)Kld + k0 + gs * 8;
            __builtin_amdgcn_global_load_lds((const AS1 void*)(A + aoff),
                (AS3 void*)((char*)As + chunk * 16), 16, 0, 0);
        }
        constexpr int QB = BN * 8 / THREADS;
        #pragma unroll
        for (int q = 0; q < QB; ++q) {
            const int chunk = q * THREADS + tid;
            const int row = chunk >> 3;
            const int slot = chunk & 7;
            const int gs = slot ^ (row & 7);
            const size_t boff = (bRow0 + row) * (size_t)Kld + k0 + gs * 8;
            __builtin_amdgcn_global_load_lds((const AS1 void*)(Bt + boff),
                (AS3 void*)((char*)Bs + chunk * 16), 16, 0, 0);
        }
        __syncthreads();   // drains vmcnt(0): staged data visible

        #pragma unroll
        for (int kk = 0; kk < 2; ++kk) {
            const int sw = ((kk * 4 + (lane >> 4)) ^ (lane & 7)) * 16;
            f16x8 af[M_REP], bf[4];
            #pragma unroll
            for (int i = 0; i < M_REP; ++i) {
                const int row = wm + i * 16 + (lane & 15);
                af[i] = *(const f16x8*)((const char*)As + row * 128 + sw);
            }
            #pragma unroll
            for (int j = 0; j < 4; ++j) {
                const int row = wn + j * 16 + (lane & 15);
                bf[j] = *(const f16x8*)((const char*)Bs + row * 128 + sw);
            }
            #pragma unroll
            for (int i = 0; i < M_REP; ++i)
                #pragma unroll
                for (int j = 0; j < 4; ++j)
                    acc[i][j] = __builtin_amdgcn_mfma_f32_16x16x32_f16(
                        af[i], bf[j], acc[i][j], 0, 0, 0);
        }
        __syncthreads();   // all reads done before next staging overwrites
    }

    // epilogue: C/D layout col=lane&15, row=(lane>>4)*4+r
    const int col_l = lane & 15, row_l = (lane >> 4) * 4;
    #pragma unroll
    for (int i = 0; i < M_REP; ++i) {
        #pragma unroll
        for (int j = 0; j < 4; ++j) {
            #pragma unroll
            for (int r = 0; r < 4; ++r) {
                const int row = bm * BM + wm + i * 16 + row_l + r;
                const int col = bn * BN + wn + j * 16 + col_l;
                const float v = acc[i][j][r];
                if (EPI == 0) {
                    Cf[(size_t)row * N + col] = v;
                } else if (EPI == 2) {
                    Cf[(size_t)row * N + col] += v;
                } else if (EPI == 4) {
                    const float t = v + bias[col];
                    const float gelu = 0.5f * t * (1.0f + erff(t * 0.70710678118654752f));
                    Ch[(size_t)row * N + col] = (_Float16)gelu;
                } else if (EPI == 6) {
                    if (col < 3072)      Cf [(size_t)row * 3072 + col] = v;
                    else if (col < 5120) Cf2[(size_t)row * 2048 + (col - 3072)] = v + bias[col - 3072];
                    else                 Cf3[(size_t)row * 1024 + (col - 5120)] = v;
                }
            }
        }
    }
}

// ---------------------------------------------------------------- host
extern "C" void kernel_launch(void* const* d_in, const int* in_sizes, int n_in,
                              void* d_out, int out_size, void* d_ws, size_t ws_size,
                              hipStream_t stream)
{
    const int*   tokens = (const int*)d_in[0];
    const float* emb  = (const float*)d_in[1];
    const float* g1   = (const float*)d_in[2];
    const float* Wqkv = (const float*)d_in[3];
    const float* Wa   = (const float*)d_in[4];
    const float* ba   = (const float*)d_in[5];
    const float* Wg   = (const float*)d_in[6];
    const float* Wo   = (const float*)d_in[7];
    const float* g2   = (const float*)d_in[8];
    const float* W1   = (const float*)d_in[9];
    const float* b1   = (const float*)d_in[10];
    const float* W2   = (const float*)d_in[11];
    const float* b2   = (const float*)d_in[12];
    const float* gf   = (const float*)d_in[13];
    const float* Wl   = (const float*)d_in[14];
    float* out = (float*)d_out;

    char* ws = (char*)d_ws;
    size_t off = 0;
    auto take = [&](size_t bytes) {
        char* p = ws + off; off += (bytes + 255) & ~(size_t)255; return p;
    };

    // fp16 weights
    _Float16* wcat = (_Float16*)take((size_t)4 * 6144 * 1024 * 2);   // [Wqkv|Wa|Wg]^T per layer
    _Float16* wo   = (_Float16*)take((size_t)4 * 1024 * 1024 * 2);
    _Float16* w1   = (_Float16*)take((size_t)4 * 4096 * 1024 * 2);
    _Float16* w2   = (_Float16*)take((size_t)4 * 1024 * 4096 * 2);
    // region shared by 4x16MiB scan scratch (layers) and Wl fp16 (62.5MiB, end)
    char*     wlRegion = take((size_t)64 << 20);
    _Float16* wl   = (_Float16*)wlRegion;
    float*    x    = (float*)take((size_t)4096 * 1024 * 4);
    _Float16* xn   = (_Float16*)take((size_t)4096 * 1024 * 2);
    float*    qkvb = (float*)take((size_t)4096 * 3072 * 4);   // 48MiB (also hosts h fp16 33.5MiB)
    float*    alb  = (float*)take((size_t)4096 * 2048 * 4);   // 32MiB (al / yT+gated / W2 partials)
    float*    G    = (float*)take((size_t)4096 * 1024 * 4);   // 16MiB

    float* qT   = (float*)wlRegion;
    float* kvT  = (float*)(wlRegion + ((size_t)16 << 20));
    float* aReT = (float*)(wlRegion + ((size_t)32 << 20));
    float* aImT = (float*)(wlRegion + ((size_t)48 << 20));
    float*    yT    = alb;                                           // [0,16MiB)
    _Float16* gated = (_Float16*)((char*)alb + ((size_t)16 << 20));  // 8.4MiB
    _Float16* h     = (_Float16*)qkvb;                               // 33.5MiB
    float*    part  = alb;   // W2 split-K partials: 2 x 16MiB (al/yT/gated dead)

    const dim3 blk(256);

    // weight transposes (f32 [K][N] -> fp16 [N][K])
    transpose_f16_kernel<<<dim3(32,  96, 4), blk, 0, stream>>>(Wqkv, wcat,               1024, 3072, (size_t)6144 * 1024);
    transpose_f16_kernel<<<dim3(32,  64, 4), blk, 0, stream>>>(Wa,   wcat + 3072 * 1024, 1024, 2048, (size_t)6144 * 1024);
    transpose_f16_kernel<<<dim3(32,  32, 4), blk, 0, stream>>>(Wg,   wcat + 5120 * 1024, 1024, 1024, (size_t)6144 * 1024);
    transpose_f16_kernel<<<dim3(32,  32, 4), blk, 0, stream>>>(Wo,   wo,  1024, 1024, (size_t)1024 * 1024);
    transpose_f16_kernel<<<dim3(32, 128, 4), blk, 0, stream>>>(W1,   w1,  1024, 4096, (size_t)4096 * 1024);
    transpose_f16_kernel<<<dim3(128, 32, 4), blk, 0, stream>>>(W2,   w2,  4096, 1024, (size_t)1024 * 4096);

    // embed + rms(g1[0]) fused (block == one row)
    embed_rms_kernel<<<4096, blk, 0, stream>>>(tokens, emb, g1, x, xn);

    for (int i = 0; i < 4; ++i) {
        gemm_kernel<6, 256, 128, 64><<<dim3(16, 48), dim3(512), 0, stream>>>(
            xn, wcat + (size_t)i * 6144 * 1024, ba + i * 2048,
            qkvb, alb, G, nullptr, 4096, 6144, 1024, 1024);
        prep_qkv_kernel<<<dim3(64, 32, 2), blk, 0, stream>>>(qkvb, qT, kvT);
        prep_a_kernel<<<dim3(64, 32, 2), blk, 0, stream>>>(alb, aReT, aImT);
        scanT_kernel<<<2048, blk, 0, stream>>>(kvT, aReT, aImT, qT, yT);
        gate_kernel<<<dim3(64, 32, 2), blk, 0, stream>>>(G, yT, gated);
        gemm_kernel<2, 128, 128, 64><<<dim3(32, 8), blk, 0, stream>>>(
            gated, wo + (size_t)i * 1024 * 1024, nullptr,
            x, nullptr, nullptr, nullptr, 4096, 1024, 1024, 1024);
        rms_f16_kernel<<<4096, blk, 0, stream>>>(x, g2 + i * 1024, xn);
        gemm_kernel<4, 256, 128, 64><<<dim3(16, 32), dim3(512), 0, stream>>>(
            xn, w1 + (size_t)i * 4096 * 1024, b1 + i * 4096,
            nullptr, nullptr, nullptr, h, 4096, 4096, 1024, 1024);
        // W2 split-K=2: partials, then fused combine(+bias, +=x) + next RMS
        gemm_kernel<0, 256, 128, 64><<<dim3(16, 8, 2), dim3(512), 0, stream>>>(
            h, w2 + (size_t)i * 1024 * 4096, nullptr,
            part, nullptr, nullptr, nullptr, 4096, 1024, 2048, 4096);
        const float* gnext = (i < 3) ? (g1 + (i + 1) * 1024) : gf;
        combine2_rms_kernel<<<4096, blk, 0, stream>>>(part, b2 + i * 1024, gnext, x, xn);
    }

    // Wl transpose deferred: its region was scan scratch during the layers
    transpose_f16_kernel<<<dim3(32, 1000, 1), blk, 0, stream>>>(Wl, wl, 1024, 32000, 0);

    // xn already holds rms(x, gf) from the last combine2_rms
    gemm_kernel<0, 256, 128, 64><<<dim3(16, 250), dim3(512), 0, stream>>>(
        xn, wl, nullptr, out, nullptr, nullptr, nullptr, 4096, 32000, 1024, 1024);
}